// Round 3
// baseline (262.614 us; speedup 1.0000x reference)
//
#include <hip/hip_runtime.h>
#include <hip/hip_bf16.h>

typedef __bf16 bf16_t;
typedef __bf16 bf16x8 __attribute__((ext_vector_type(8)));
typedef __bf16 bf16x4 __attribute__((ext_vector_type(4)));
typedef float f32x4 __attribute__((ext_vector_type(4)));

#define IN_DIM 21
#define HID 512
#define OUT_DIM 21
#define M_TILE 64
#define LSTRIDE 520   // 65 x 16B units per row: odd unit stride spreads b128 bank groups
#define THREADS 512   // 8 waves; LDS ~70.7 KB -> 2 blocks/CU -> 16 waves/CU (50% cap)

// ---- prep: fp32 -> bf16 fragment-major weights (A/B frag layouts are identical) ----
// frag element (idx = tile*16 + (lane&15), k = k0 + (lane>>4)*8 + j) at base + lane*8 + j.
// W2f: [kstep(16)][htile(32)][512]   W1f: [htile(32)][512] (k>=21 zero)
// W3f: [kstep(16)][otile(2)][512]    (o>=21 zero)
__global__ void prep_kernel(const float* __restrict__ W1, const float* __restrict__ W2,
                            const float* __restrict__ W3,
                            bf16_t* __restrict__ W1f, bf16_t* __restrict__ W2f,
                            bf16_t* __restrict__ W3f) {
    int i = blockIdx.x * blockDim.x + threadIdx.x;
    int stride = gridDim.x * blockDim.x;
    const int NW2 = HID * HID;     // 262144
    const int NW1 = 32 * 512;      // 16384
    const int NW3 = 16 * 2 * 512;  // 16384
    for (; i < NW2 + NW1 + NW3; i += stride) {
        if (i < NW2) {
            int j = i & 7, lane = (i >> 3) & 63, ht = (i >> 9) & 31, kstep = i >> 14;
            int n = ht * 16 + (lane & 15);
            int k = kstep * 32 + (lane >> 4) * 8 + j;
            W2f[i] = (bf16_t)W2[n * HID + k];
        } else if (i < NW2 + NW1) {
            int t = i - NW2;
            int j = t & 7, lane = (t >> 3) & 63, ht = t >> 9;
            int n = ht * 16 + (lane & 15);
            int k = (lane >> 4) * 8 + j;
            W1f[t] = (k < IN_DIM) ? (bf16_t)W1[n * IN_DIM + k] : (bf16_t)0.0f;
        } else {
            int t = i - NW2 - NW1;
            int j = t & 7, lane = (t >> 3) & 63, ot = (t >> 9) & 1, kstep = t >> 10;
            int o = ot * 16 + (lane & 15);
            int k = kstep * 32 + (lane >> 4) * 8 + j;
            W3f[t] = (o < OUT_DIM) ? (bf16_t)W3[o * HID + k] : (bf16_t)0.0f;
        }
    }
}

// ---- fused MLP + loss, operand-swapped: D[hidden][batch] ----
__global__ __launch_bounds__(THREADS, 4)
void fused_kernel(const float* __restrict__ V, const float* __restrict__ gt,
                  const float* __restrict__ b1, const float* __restrict__ b2,
                  const float* __restrict__ b3,
                  const bf16_t* __restrict__ W1f, const bf16_t* __restrict__ W2f,
                  const bf16_t* __restrict__ W3f, float* __restrict__ accum,
                  unsigned int* __restrict__ counter, float* __restrict__ out,
                  int nblocks) {
    __shared__ __align__(16) bf16_t vlds[M_TILE][32];
    __shared__ __align__(16) bf16_t h[M_TILE][LSTRIDE];   // h1, then h2 (reused)
    __shared__ float redbuf[16];

    const int tid  = threadIdx.x;
    const int wave = tid >> 6;       // 0..7 ; owns hidden channels [wave*64, wave*64+64)
    const int lane = tid & 63;
    const int quad = lane >> 4;
    const int l16  = lane & 15;
    const long row0 = (long)blockIdx.x * M_TILE;

    // phase 0: velocities tile -> LDS bf16 [batch][32], k padded with zeros
    for (int idx = tid; idx < M_TILE * 32; idx += THREADS) {
        int r = idx >> 5, c = idx & 31;
        float v = (c < IN_DIM) ? V[(row0 + r) * IN_DIM + c] : 0.0f;
        vlds[r][c] = (bf16_t)v;
    }
    __syncthreads();

    // phase 1: h1[batch][hid] = relu(W1 @ V^T + b1), D[m=hid][n=batch]
    {
        bf16x8 bfrag[4];
        #pragma unroll
        for (int nt = 0; nt < 4; ++nt)
            bfrag[nt] = *reinterpret_cast<const bf16x8*>(&vlds[nt * 16 + l16][quad * 8]);
        #pragma unroll
        for (int mt = 0; mt < 4; ++mt) {
            bf16x8 a = *reinterpret_cast<const bf16x8*>(W1f + (wave * 4 + mt) * 512 + lane * 8);
            f32x4 bias = *reinterpret_cast<const f32x4*>(b1 + wave * 64 + mt * 16 + quad * 4);
            #pragma unroll
            for (int nt = 0; nt < 4; ++nt) {
                f32x4 c = {0.0f, 0.0f, 0.0f, 0.0f};
                c = __builtin_amdgcn_mfma_f32_16x16x32_bf16(a, bfrag[nt], c, 0, 0, 0);
                bf16x4 hv;
                #pragma unroll
                for (int r = 0; r < 4; ++r) {
                    float v = c[r] + bias[r];
                    hv[r] = (bf16_t)(v > 0.0f ? v : 0.0f);
                }
                *reinterpret_cast<bf16x4*>(&h[nt * 16 + l16][wave * 64 + mt * 16 + quad * 4]) = hv;
            }
        }
    }
    __syncthreads();

    // phase 2: h2 = relu(W2 @ h1^T + b2). Per wave: 64 hid_out x 64 batch, K=512.
    f32x4 acc[4][4];
    #pragma unroll
    for (int mt = 0; mt < 4; ++mt)
        #pragma unroll
        for (int nt = 0; nt < 4; ++nt)
            acc[mt][nt] = (f32x4){0.0f, 0.0f, 0.0f, 0.0f};

    for (int ks = 0; ks < 16; ++ks) {
        bf16x8 bfrag[4];
        #pragma unroll
        for (int nt = 0; nt < 4; ++nt)
            bfrag[nt] = *reinterpret_cast<const bf16x8*>(&h[nt * 16 + l16][ks * 32 + quad * 8]);
        #pragma unroll
        for (int mt = 0; mt < 4; ++mt) {
            bf16x8 a = *reinterpret_cast<const bf16x8*>(
                W2f + ks * 16384 + (wave * 4 + mt) * 512 + lane * 8);
            #pragma unroll
            for (int nt = 0; nt < 4; ++nt)
                acc[mt][nt] = __builtin_amdgcn_mfma_f32_16x16x32_bf16(a, bfrag[nt], acc[mt][nt], 0, 0, 0);
        }
    }
    __syncthreads();   // all h1 reads complete before overwrite

    #pragma unroll
    for (int mt = 0; mt < 4; ++mt) {
        f32x4 bias = *reinterpret_cast<const f32x4*>(b2 + wave * 64 + mt * 16 + quad * 4);
        #pragma unroll
        for (int nt = 0; nt < 4; ++nt) {
            bf16x4 hv;
            #pragma unroll
            for (int r = 0; r < 4; ++r) {
                float v = acc[mt][nt][r] + bias[r];
                hv[r] = (bf16_t)(v > 0.0f ? v : 0.0f);
            }
            *reinterpret_cast<bf16x4*>(&h[nt * 16 + l16][wave * 64 + mt * 16 + quad * 4]) = hv;
        }
    }
    __syncthreads();

    // phase 3: out = W3 @ h2^T + b3. 8 jobs = 2 o-tiles x 4 batch-tiles, one per wave.
    {
        const int ot = wave & 1;
        const int nt = wave >> 1;
        f32x4 acc3 = {0.0f, 0.0f, 0.0f, 0.0f};
        for (int ks = 0; ks < 16; ++ks) {
            bf16x8 a = *reinterpret_cast<const bf16x8*>(W3f + (ks * 2 + ot) * 512 + lane * 8);
            bf16x8 b = *reinterpret_cast<const bf16x8*>(&h[nt * 16 + l16][ks * 32 + quad * 8]);
            acc3 = __builtin_amdgcn_mfma_f32_16x16x32_bf16(a, b, acc3, 0, 0, 0);
        }

        float num = 0.0f, den = 0.0f;
        long brow = row0 + nt * 16 + l16;
        #pragma unroll
        for (int r = 0; r < 4; ++r) {
            int c = ot * 16 + quad * 4 + r;
            if (c < OUT_DIM) {
                float pred = acc3[r] + b3[c];
                float g = gt[brow * OUT_DIM + c];
                if (g > -5000.0f) {
                    float w = (floorf(pred * 2.0f) == floorf(g * 2.0f)) ? 0.5f : 1.0f;
                    num += fabsf(pred * w - g * w);
                    den += 1.0f;
                }
            }
        }
        #pragma unroll
        for (int off = 32; off > 0; off >>= 1) {
            num += __shfl_down(num, off);
            den += __shfl_down(den, off);
        }
        if (lane == 0) { redbuf[wave * 2] = num; redbuf[wave * 2 + 1] = den; }
    }
    __syncthreads();
    if (tid == 0) {
        float n8 = 0.0f, d8 = 0.0f;
        #pragma unroll
        for (int w = 0; w < 8; ++w) { n8 += redbuf[w * 2]; d8 += redbuf[w * 2 + 1]; }
        atomicAdd(accum, n8);
        atomicAdd(accum + 1, d8);
        __threadfence();
        unsigned int ticket = atomicAdd(counter, 1u);
        if (ticket == (unsigned int)(nblocks - 1)) {
            float tn = atomicAdd(accum, 0.0f);      // device-scope atomic read
            float td = atomicAdd(accum + 1, 0.0f);
            out[0] = tn / td;
        }
    }
}

extern "C" void kernel_launch(void* const* d_in, const int* in_sizes, int n_in,
                              void* d_out, int out_size, void* d_ws, size_t ws_size,
                              hipStream_t stream) {
    const float* V  = (const float*)d_in[0];
    const float* gt = (const float*)d_in[1];
    const float* W1 = (const float*)d_in[2];
    const float* b1 = (const float*)d_in[3];
    const float* W2 = (const float*)d_in[4];
    const float* b2 = (const float*)d_in[5];
    const float* W3 = (const float*)d_in[6];
    const float* b3 = (const float*)d_in[7];
    float* out = (float*)d_out;

    char* ws = (char*)d_ws;
    float* accum = (float*)ws;                     // [0]=num, [1]=den
    unsigned int* counter = (unsigned int*)(ws + 8);
    bf16_t* W2f = (bf16_t*)(ws + 16);
    bf16_t* W1f = (bf16_t*)(ws + 16 + 512 * 512 * 2);
    bf16_t* W3f = (bf16_t*)(ws + 16 + 512 * 512 * 2 + 32 * 512 * 2);

    int Brows = in_sizes[0] / IN_DIM;   // 131072
    int grid = Brows / M_TILE;          // 2048

    hipMemsetAsync(ws, 0, 16, stream);  // num, den, counter
    prep_kernel<<<576, 512, 0, stream>>>(W1, W2, W3, W1f, W2f, W3f);
    fused_kernel<<<grid, THREADS, 0, stream>>>(V, gt, b1, b2, b3, W1f, W2f, W3f,
                                               accum, counter, out, grid);
}

// Round 4
// 235.359 us; speedup vs baseline: 1.1158x; 1.1158x over previous
//
#include <hip/hip_runtime.h>
#include <hip/hip_bf16.h>

typedef __bf16 bf16_t;
typedef __bf16 bf16x8 __attribute__((ext_vector_type(8)));
typedef __bf16 bf16x4 __attribute__((ext_vector_type(4)));
typedef float f32x4 __attribute__((ext_vector_type(4)));

#define IN_DIM 21
#define HID 512
#define OUT_DIM 21
#define M_TILE 64
#define LSTRIDE 520   // 65 x 16B units per row (odd -> spreads b128 bank groups, 2-way max)
#define VPAD 40       // vlds row = 80 B = 20 dwords (odd vs 32 banks -> 2-way max)
#define THREADS 1024  // 16 waves; f=2 partition, spill-free (acc 32 regs/wave)

// ---- prep: fp32 -> bf16 fragment-major weights (A/B frag layouts identical) ----
// frag element (idx = tile*16 + (lane&15), k = k0 + (lane>>4)*8 + j) at base + lane*8 + j.
// W2f: [kstep(16)][htile(32)][512]   W1f: [htile(32)][512] (k>=21 zero)
// W3f: [kstep(16)][otile(2)][512]    (o>=21 zero)
__global__ void prep_kernel(const float* __restrict__ W1, const float* __restrict__ W2,
                            const float* __restrict__ W3,
                            bf16_t* __restrict__ W1f, bf16_t* __restrict__ W2f,
                            bf16_t* __restrict__ W3f) {
    int i = blockIdx.x * blockDim.x + threadIdx.x;
    int stride = gridDim.x * blockDim.x;
    const int NW2 = HID * HID;     // 262144
    const int NW1 = 32 * 512;      // 16384
    const int NW3 = 16 * 2 * 512;  // 16384
    for (; i < NW2 + NW1 + NW3; i += stride) {
        if (i < NW2) {
            int j = i & 7, lane = (i >> 3) & 63, ht = (i >> 9) & 31, kstep = i >> 14;
            int n = ht * 16 + (lane & 15);
            int k = kstep * 32 + (lane >> 4) * 8 + j;
            W2f[i] = (bf16_t)W2[n * HID + k];
        } else if (i < NW2 + NW1) {
            int t = i - NW2;
            int j = t & 7, lane = (t >> 3) & 63, ht = t >> 9;
            int n = ht * 16 + (lane & 15);
            int k = (lane >> 4) * 8 + j;
            W1f[t] = (k < IN_DIM) ? (bf16_t)W1[n * IN_DIM + k] : (bf16_t)0.0f;
        } else {
            int t = i - NW2 - NW1;
            int j = t & 7, lane = (t >> 3) & 63, ot = (t >> 9) & 1, kstep = t >> 10;
            int o = ot * 16 + (lane & 15);
            int k = kstep * 32 + (lane >> 4) * 8 + j;
            W3f[t] = (o < OUT_DIM) ? (bf16_t)W3[o * HID + k] : (bf16_t)0.0f;
        }
    }
}

// ---- fused MLP + loss, operand-swapped (D[m=hidden][n=batch]), f=2, prefetched ----
__global__ __launch_bounds__(THREADS)
void fused_kernel(const float* __restrict__ V, const float* __restrict__ gt,
                  const float* __restrict__ b1, const float* __restrict__ b2,
                  const float* __restrict__ b3,
                  const bf16_t* __restrict__ W1f, const bf16_t* __restrict__ W2f,
                  const bf16_t* __restrict__ W3f, float* __restrict__ accum,
                  unsigned int* __restrict__ counter, float* __restrict__ out,
                  int nblocks) {
    __shared__ __align__(16) bf16_t vlds[M_TILE][VPAD];
    __shared__ __align__(16) bf16_t h[M_TILE][LSTRIDE];   // h1, then h2 (reused)
    __shared__ float redbuf[16];

    const int tid  = threadIdx.x;
    const int wave = tid >> 6;       // 0..15; owns hidden [wave*32, wave*32+32)
    const int lane = tid & 63;
    const int quad = lane >> 4;
    const int l16  = lane & 15;
    const long row0 = (long)blockIdx.x * M_TILE;

    // ---- early prefetches (independent of LDS) ----
    bf16x8 w1a0 = *reinterpret_cast<const bf16x8*>(W1f + (wave * 2 + 0) * 512 + lane * 8);
    bf16x8 w1a1 = *reinterpret_cast<const bf16x8*>(W1f + (wave * 2 + 1) * 512 + lane * 8);

    int ot = 0, ntj = 0;
    float gpre[4] = {0.0f, 0.0f, 0.0f, 0.0f};
    float bpre[4] = {0.0f, 0.0f, 0.0f, 0.0f};
    if (wave < 8) {
        ot  = wave & 1;
        ntj = wave >> 1;
        long brow = row0 + ntj * 16 + l16;
        #pragma unroll
        for (int r = 0; r < 4; ++r) {
            int c = ot * 16 + quad * 4 + r;
            if (c < OUT_DIM) {
                gpre[r] = gt[brow * OUT_DIM + c];
                bpre[r] = b3[c];
            }
        }
    }

    // phase 0: velocities tile -> LDS bf16 [batch][VPAD], k cols 21..31 zero
    for (int idx = tid; idx < M_TILE * 32; idx += THREADS) {
        int r = idx >> 5, c = idx & 31;
        float v = (c < IN_DIM) ? V[(row0 + r) * IN_DIM + c] : 0.0f;
        vlds[r][c] = (bf16_t)v;
    }
    __syncthreads();

    // phase 1: h1 = relu(W1 @ V^T + b1)
    {
        bf16x8 bfrag[4];
        #pragma unroll
        for (int nt = 0; nt < 4; ++nt)
            bfrag[nt] = *reinterpret_cast<const bf16x8*>(&vlds[nt * 16 + l16][quad * 8]);
        #pragma unroll
        for (int t = 0; t < 2; ++t) {
            bf16x8 a = t ? w1a1 : w1a0;
            f32x4 bias = *reinterpret_cast<const f32x4*>(b1 + wave * 32 + t * 16 + quad * 4);
            #pragma unroll
            for (int nt = 0; nt < 4; ++nt) {
                f32x4 c = {0.0f, 0.0f, 0.0f, 0.0f};
                c = __builtin_amdgcn_mfma_f32_16x16x32_bf16(a, bfrag[nt], c, 0, 0, 0);
                bf16x4 hv;
                #pragma unroll
                for (int r = 0; r < 4; ++r) {
                    float v = c[r] + bias[r];
                    hv[r] = (bf16_t)(v > 0.0f ? v : 0.0f);
                }
                *reinterpret_cast<bf16x4*>(&h[nt * 16 + l16][wave * 32 + t * 16 + quad * 4]) = hv;
            }
        }
    }
    __syncthreads();

    // phase 2: h2 = relu(W2 @ h1^T + b2). Per wave: 32 hid_out x 64 batch, K=512.
    f32x4 acc[2][4];
    #pragma unroll
    for (int t = 0; t < 2; ++t)
        #pragma unroll
        for (int nt = 0; nt < 4; ++nt)
            acc[t][nt] = (f32x4){0.0f, 0.0f, 0.0f, 0.0f};

    {
        const bf16_t* wp0 = W2f + (wave * 2 + 0) * 512 + lane * 8;
        const bf16_t* wp1 = W2f + (wave * 2 + 1) * 512 + lane * 8;
        bf16x8 a0 = *reinterpret_cast<const bf16x8*>(wp0);
        bf16x8 a1 = *reinterpret_cast<const bf16x8*>(wp1);
        #pragma unroll
        for (int ks = 0; ks < 16; ++ks) {
            bf16x8 a0c = a0, a1c = a1;
            if (ks < 15) {  // depth-1 prefetch of next K-step's A-frags
                a0 = *reinterpret_cast<const bf16x8*>(wp0 + (ks + 1) * 16384);
                a1 = *reinterpret_cast<const bf16x8*>(wp1 + (ks + 1) * 16384);
            }
            bf16x8 bfrag[4];
            #pragma unroll
            for (int nt = 0; nt < 4; ++nt)
                bfrag[nt] = *reinterpret_cast<const bf16x8*>(&h[nt * 16 + l16][ks * 32 + quad * 8]);
            #pragma unroll
            for (int nt = 0; nt < 4; ++nt) {
                acc[0][nt] = __builtin_amdgcn_mfma_f32_16x16x32_bf16(a0c, bfrag[nt], acc[0][nt], 0, 0, 0);
                acc[1][nt] = __builtin_amdgcn_mfma_f32_16x16x32_bf16(a1c, bfrag[nt], acc[1][nt], 0, 0, 0);
            }
        }
    }

    // prefetch first W3 frag while waiting at the barrier (waves 0..7)
    bf16x8 w3 = {};
    const bf16_t* wp3 = W3f + ot * 512 + lane * 8;
    if (wave < 8) w3 = *reinterpret_cast<const bf16x8*>(wp3);

    __syncthreads();   // all h1 reads complete before overwrite

    #pragma unroll
    for (int t = 0; t < 2; ++t) {
        f32x4 bias = *reinterpret_cast<const f32x4*>(b2 + wave * 32 + t * 16 + quad * 4);
        #pragma unroll
        for (int nt = 0; nt < 4; ++nt) {
            bf16x4 hv;
            #pragma unroll
            for (int r = 0; r < 4; ++r) {
                float v = acc[t][nt][r] + bias[r];
                hv[r] = (bf16_t)(v > 0.0f ? v : 0.0f);
            }
            *reinterpret_cast<bf16x4*>(&h[nt * 16 + l16][wave * 32 + t * 16 + quad * 4]) = hv;
        }
    }
    __syncthreads();

    // phase 3: out = W3 @ h2^T + b3. 8 jobs = 2 o-tiles x 4 batch-tiles on waves 0..7.
    if (wave < 8) {
        f32x4 acc3 = {0.0f, 0.0f, 0.0f, 0.0f};
        #pragma unroll
        for (int ks = 0; ks < 16; ++ks) {
            bf16x8 w3c = w3;
            if (ks < 15) w3 = *reinterpret_cast<const bf16x8*>(wp3 + (ks + 1) * 1024);
            bf16x8 b = *reinterpret_cast<const bf16x8*>(&h[ntj * 16 + l16][ks * 32 + quad * 8]);
            acc3 = __builtin_amdgcn_mfma_f32_16x16x32_bf16(w3c, b, acc3, 0, 0, 0);
        }

        float num = 0.0f, den = 0.0f;
        #pragma unroll
        for (int r = 0; r < 4; ++r) {
            int c = ot * 16 + quad * 4 + r;
            if (c < OUT_DIM) {
                float pred = acc3[r] + bpre[r];
                float g = gpre[r];
                if (g > -5000.0f) {
                    float w = (floorf(pred * 2.0f) == floorf(g * 2.0f)) ? 0.5f : 1.0f;
                    num += fabsf(pred * w - g * w);
                    den += 1.0f;
                }
            }
        }
        #pragma unroll
        for (int off = 32; off > 0; off >>= 1) {
            num += __shfl_down(num, off);
            den += __shfl_down(den, off);
        }
        if (lane == 0) { redbuf[wave * 2] = num; redbuf[wave * 2 + 1] = den; }
    }
    __syncthreads();
    if (tid == 0) {
        float n8 = 0.0f, d8 = 0.0f;
        #pragma unroll
        for (int w = 0; w < 8; ++w) { n8 += redbuf[w * 2]; d8 += redbuf[w * 2 + 1]; }
        atomicAdd(accum, n8);
        atomicAdd(accum + 1, d8);
        __threadfence();
        unsigned int ticket = atomicAdd(counter, 1u);
        if (ticket == (unsigned int)(nblocks - 1)) {
            float tn = atomicAdd(accum, 0.0f);      // device-scope atomic read
            float td = atomicAdd(accum + 1, 0.0f);
            out[0] = tn / td;
        }
    }
}

extern "C" void kernel_launch(void* const* d_in, const int* in_sizes, int n_in,
                              void* d_out, int out_size, void* d_ws, size_t ws_size,
                              hipStream_t stream) {
    const float* V  = (const float*)d_in[0];
    const float* gt = (const float*)d_in[1];
    const float* W1 = (const float*)d_in[2];
    const float* b1 = (const float*)d_in[3];
    const float* W2 = (const float*)d_in[4];
    const float* b2 = (const float*)d_in[5];
    const float* W3 = (const float*)d_in[6];
    const float* b3 = (const float*)d_in[7];
    float* out = (float*)d_out;

    char* ws = (char*)d_ws;
    float* accum = (float*)ws;                     // [0]=num, [1]=den
    unsigned int* counter = (unsigned int*)(ws + 8);
    bf16_t* W2f = (bf16_t*)(ws + 16);
    bf16_t* W1f = (bf16_t*)(ws + 16 + 512 * 512 * 2);
    bf16_t* W3f = (bf16_t*)(ws + 16 + 512 * 512 * 2 + 32 * 512 * 2);

    int Brows = in_sizes[0] / IN_DIM;   // 131072
    int grid = Brows / M_TILE;          // 2048

    hipMemsetAsync(ws, 0, 16, stream);  // num, den, counter
    prep_kernel<<<576, 512, 0, stream>>>(W1, W2, W3, W1f, W2f, W3f);
    fused_kernel<<<grid, THREADS, 0, stream>>>(V, gt, b1, b2, b3, W1f, W2f, W3f,
                                               accum, counter, out, grid);
}